// Round 16
// baseline (257.138 us; speedup 1.0000x reference)
//
#include <hip/hip_runtime.h>

typedef __attribute__((ext_vector_type(8))) __bf16 bf16x8;
typedef __attribute__((ext_vector_type(4))) float f32x4;

constexpr int BB = 16, NN = 906, CC = 768, HH = 12, MM1 = 513;
constexpr int MTOK = BB * NN;      // 14496 tokens
constexpr int TOKC = MTOK * CC;    // 11132928 elements

#define MFMA16(a, b, c) __builtin_amdgcn_mfma_f32_16x16x32_bf16((a), (b), (c), 0, 0, 0)

__device__ __forceinline__ void glds16(const void* g, void* l) {
  __builtin_amdgcn_global_load_lds(
      (const __attribute__((address_space(1))) void*)g,
      (__attribute__((address_space(3))) void*)l, 16, 0, 0);
}

__device__ __forceinline__ unsigned pack2(float a, float b) {
  unsigned short ua = __builtin_bit_cast(unsigned short, (__bf16)a);
  unsigned short ub = __builtin_bit_cast(unsigned short, (__bf16)b);
  return (unsigned)ua | ((unsigned)ub << 16);
}

union U8 { unsigned u[4]; bf16x8 v; };

// ------- merged convert kernel: blocks [0,5436) cvt_x ; [5436,8316) cvt_w -------
constexpr int CVTX_BLOCKS = TOKC / 2048;          // 5436
constexpr int CVTW_BLOCKS = 24 * 24 * 5;          // 2880
__global__ __launch_bounds__(256) void cvt_all_kernel(
    const float* __restrict__ x, __bf16* __restrict__ xb,
    const float* __restrict__ W0, const float* __restrict__ W1,
    const float* __restrict__ W2, const float* __restrict__ W3,
    const float* __restrict__ W4, __bf16* __restrict__ wout) {
  __shared__ float t[32][33];
  const int bid = blockIdx.x;
  if (bid < CVTX_BLOCKS) {
    long i = (long)bid * 256 + threadIdx.x;
    const float4* p = (const float4*)x + i * 2;
    float4 a = p[0], b = p[1];
    bf16x8 o;
    o[0] = (__bf16)a.x; o[1] = (__bf16)a.y; o[2] = (__bf16)a.z; o[3] = (__bf16)a.w;
    o[4] = (__bf16)b.x; o[5] = (__bf16)b.y; o[6] = (__bf16)b.z; o[7] = (__bf16)b.w;
    *(bf16x8*)(xb + i * 8) = o;
  } else {
    int wb = bid - CVTX_BLOCKS;
    int z = wb / 576, rem = wb - z * 576;
    int by = rem / 24, bx = rem - by * 24;
    const float* src = z == 0 ? W0 : z == 1 ? W1 : z == 2 ? W2 : z == 3 ? W3 : W4;
    __bf16* dst = wout + (size_t)z * CC * CC;
    int x0 = bx * 32, y0 = by * 32;
    int tx = threadIdx.x & 31, ty = threadIdx.x >> 5;  // ty 0..7
#pragma unroll
    for (int i = 0; i < 4; ++i)
      t[ty + i * 8][tx] = src[(size_t)(y0 + ty + i * 8) * CC + x0 + tx];
    __syncthreads();
#pragma unroll
    for (int i = 0; i < 4; ++i)
      dst[(size_t)(x0 + ty + i * 8) * CC + y0 + tx] = (__bf16)t[tx][ty + i * 8];
  }
}

// ======== QKV GEMM: 512-thr 256x256 tile, wave 128x64, schedule-B sync ========
// LDS-BW fix: wave tile 128x64 (acc[8][4]) reuses each A-frag across 4 B-frags:
// 24 ds_read_b128 per 64 MFMA (was 16 per 32) -> 500 B LDS/MFMA (was 750).
// Sync structure is schedule-B VERBATIM: prologue STAGE(0); iter t: STAGE(t+1)
// [8 loads/thread], vmcnt(8) retires exactly tile t, barrier, COMP(t), barrier.
// LDS 128 KB -> 1 block/CU, 8 waves = 2/SIMD (same per-SIMD TLP as before).
__global__ __launch_bounds__(512, 2) void gemm_qkv256(
    const __bf16* __restrict__ Xb, const __bf16* __restrict__ WT,
    __bf16* __restrict__ Qb, __bf16* __restrict__ Kb,
    __bf16* __restrict__ VAb, __bf16* __restrict__ VVb) {
  __shared__ alignas(16) __bf16 LA[2][16384];  // A: 256x64 per buf (32 KB)
  __shared__ alignas(16) __bf16 LB[2][16384];  // B: 256x64 per buf (32 KB)

  const int tid = threadIdx.x;
  const int l = tid & 63, w = tid >> 6;
  const int l15 = l & 15, hi = l >> 4;
  const int wm = w >> 2, wn = w & 3;          // 2m x 4n waves
  const int nt = blockIdx.x, mt = blockIdx.y;
  const int m0 = mt * 256;
  const int wi = nt / 3, nc = (nt % 3) * 256;
  const __bf16* bt = WT + (size_t)wi * (CC * CC) + (size_t)nc * CC;

  // staging map: 512 threads cover 4 row-groups of 64 (rows j*64+srow), 8 slots
  const int srow = tid >> 3, sslot = tid & 7;
  const __bf16* pA[4]; const __bf16* pB[4]; int ldst[4];
#pragma unroll
  for (int j = 0; j < 4; ++j) {
    int row = j * 64 + srow;
    int co = (sslot ^ (row & 7)) * 8;
    int arow = m0 + row; arow = arow < MTOK ? arow : MTOK - 1;
    pA[j] = Xb + (size_t)arow * CC + co;
    pB[j] = bt + (size_t)row * CC + co;
    ldst[j] = row * 64 + sslot * 8;
  }

  f32x4 acc[8][4] = {};

#define STAGE_(buf)                                                            \
  {                                                                            \
    _Pragma("unroll") for (int j = 0; j < 4; ++j) {                            \
      glds16(pA[j], &LA[buf][ldst[j]]); pA[j] += 64;                           \
      glds16(pB[j], &LB[buf][ldst[j]]); pB[j] += 64;                           \
    }                                                                          \
  }

#define COMP_(buf)                                                             \
  {                                                                            \
    _Pragma("unroll") for (int kks = 0; kks < 2; ++kks) {                      \
      bf16x8 af[8], bg[4];                                                     \
      _Pragma("unroll") for (int fm = 0; fm < 8; ++fm) {                       \
        int row = wm * 128 + fm * 16 + l15;                                    \
        af[fm] = *(const bf16x8*)(&LA[buf][row * 64 +                          \
                                           (((kks * 4 + hi) ^ (row & 7)) * 8)]);\
      }                                                                        \
      _Pragma("unroll") for (int fn = 0; fn < 4; ++fn) {                       \
        int row = wn * 64 + fn * 16 + l15;                                     \
        bg[fn] = *(const bf16x8*)(&LB[buf][row * 64 +                          \
                                           (((kks * 4 + hi) ^ (row & 7)) * 8)]);\
      }                                                                        \
      __builtin_amdgcn_s_setprio(1);                                           \
      _Pragma("unroll") for (int fm = 0; fm < 8; ++fm)                         \
          _Pragma("unroll") for (int fn = 0; fn < 4; ++fn)                     \
              acc[fm][fn] = MFMA16(af[fm], bg[fn], acc[fm][fn]);               \
      __builtin_amdgcn_s_setprio(0);                                           \
    }                                                                          \
  }

  STAGE_(0);  // tile 0 -> 8 loads in flight

#pragma unroll
  for (int t = 0; t < 12; ++t) {
    if (t < 11) {
      STAGE_((t + 1) & 1);  // 16 in flight
      asm volatile("s_waitcnt vmcnt(8)" ::: "memory");  // retire tile t only
    } else {
      asm volatile("s_waitcnt vmcnt(0)" ::: "memory");
    }
    asm volatile("s_barrier" ::: "memory");
    COMP_(t & 1);
    asm volatile("s_barrier" ::: "memory");  // close reads before next overwrite
  }
#undef STAGE_
#undef COMP_

  // epilogue: wave owns 128x64 at (wm*128, wn*64); its 64 cols = one head
  const int hq = (nt % 3) * 4 + wn;
  const float qs = (wi == 0) ? 0.1803368801f : 1.0f;  // 0.125 * log2(e)
  const int t00 = m0 + wm * 128 + hi * 4;
#pragma unroll
  for (int fm = 0; fm < 8; ++fm) {
    int tk = t00 + fm * 16;
#pragma unroll
    for (int r = 0; r < 4; ++r) {
      int token = tk + r;
      if (token >= MTOK) continue;
      int b = token / NN, n = token - b * NN;
      size_t bhd = (size_t)b * HH + hq;
#pragma unroll
      for (int fn = 0; fn < 4; ++fn) {
        int dd = fn * 16 + l15;
        __bf16 bv = (__bf16)(acc[fm][fn][r] * qs);
        if (wi == 0)      Qb[(bhd * NN + n) * 64 + dd] = bv;
        else if (wi == 1) Kb[(bhd * NN + n) * 64 + dd] = bv;
        else if (wi == 2) ((n < MM1) ? VAb : VVb)[(bhd * 64 + dd) * NN + n] = bv;
        else              ((n < MM1) ? VVb : VAb)[(bhd * 64 + dd) * NN + n] = bv;
      }
    }
  }
}

// ---------------- flash attention (round-8 structure + XCD-chunked swizzle) ----------------
__global__ __launch_bounds__(256, 2) void attn_kernel(
    const __bf16* __restrict__ Q, const __bf16* __restrict__ K,
    const __bf16* __restrict__ VA, const __bf16* __restrict__ VV,
    __bf16* __restrict__ AO) {
  __shared__ alignas(16) __bf16 K_lds[2][64 * 64];
  __shared__ alignas(16) __bf16 V_lds[2][64 * 64];  // [dd][key]

  const int tid = threadIdx.x;
  const int w = tid >> 6, l = tid & 63;
  const int l15 = l & 15, hi = l >> 4;

  // XCD-chunked decode: bid -> (bh, tile)
  const int bid = blockIdx.x;
  const int xcd = bid & 7, slot = bid >> 3;     // slot 0..383
  const int bh = xcd * 24 + (slot >> 4);        // contiguous 24-head range per XCD
  const int tile = slot & 15;

  int q0, qn; bool mod1;
  if (tile < 9) { q0 = tile * 64; qn = min(64, MM1 - q0); mod1 = true; }
  else { q0 = MM1 + (tile - 9) * 64; qn = min(64, NN - q0); mod1 = false; }

  const __bf16* qp = Q + (size_t)bh * NN * 64;
  const __bf16* kp = K + (size_t)bh * NN * 64;
  const __bf16* vp = (mod1 ? VA : VV) + (size_t)bh * 64 * NN;

  int qrow = q0 + w * 16 + l15; qrow = qrow < NN ? qrow : NN - 1;
  bf16x8 qf0 = *(const bf16x8*)(qp + (size_t)qrow * 64 + hi * 8);
  bf16x8 qf1 = *(const bf16x8*)(qp + (size_t)qrow * 64 + 32 + hi * 8);

  f32x4 Of[4] = {};
  float l_part = 0.f;  // lane-local; reduced once at epilogue

  const int srow = l >> 3, sslot = l & 7;
  auto stage = [&](int kt, int buf) {
    int k0s = kt * 64;
#pragma unroll
    for (int rr = 0; rr < 2; ++rr) {
      int row = rr * 32 + w * 8 + srow;
      int krow = k0s + row; krow = krow < NN ? krow : NN - 1;  // dup key, masked
      glds16(kp + (size_t)krow * 64 + ((sslot ^ (row & 7)) * 8),
             &K_lds[buf][row * 64 + sslot * 8]);
      int vcol = k0s + ((sslot ^ (row & 7)) * 8);  // tail overrun: P=0 there
      glds16(vp + (size_t)row * NN + vcol, &V_lds[buf][row * 64 + sslot * 8]);
    }
  };

  const bool ofirst = ((hi & 1) == 0);
  auto tilecomp = [&](const __bf16* Kb, const __bf16* Vb, bool maskTail) {
    f32x4 sa[4] = {};
    __builtin_amdgcn_s_setprio(1);
#pragma unroll
    for (int kks = 0; kks < 2; ++kks) {
#pragma unroll
      for (int f = 0; f < 4; ++f) {
        int rk = f * 16 + l15;
        bf16x8 kf = *(const bf16x8*)(Kb + rk * 64 + (((kks * 4 + hi) ^ (rk & 7)) * 8));
        sa[f] = MFMA16(kf, (kks ? qf1 : qf0), sa[f]);
      }
    }
    __builtin_amdgcn_s_setprio(0);

    if (maskTail) {
#pragma unroll
      for (int f = 0; f < 4; ++f) {
        int keyb = 896 + f * 16 + hi * 4;
#pragma unroll
        for (int r = 0; r < 4; ++r)
          if (keyb + r >= NN) sa[f][r] = -1e30f;
      }
    }

#pragma unroll
    for (int f = 0; f < 4; ++f)
#pragma unroll
      for (int r = 0; r < 4; ++r) {
        sa[f][r] = __builtin_amdgcn_exp2f(sa[f][r]);
        l_part += sa[f][r];
      }

#pragma unroll
    for (int c = 0; c < 2; ++c) {
      unsigned p00 = pack2(sa[c * 2][0], sa[c * 2][1]);
      unsigned p01 = pack2(sa[c * 2][2], sa[c * 2][3]);
      unsigned p10 = pack2(sa[c * 2 + 1][0], sa[c * 2 + 1][1]);
      unsigned p11 = pack2(sa[c * 2 + 1][2], sa[c * 2 + 1][3]);
      unsigned own0 = (hi & 1) ? p10 : p00;
      unsigned own1 = (hi & 1) ? p11 : p01;
      unsigned snd0 = (hi & 1) ? p00 : p10;
      unsigned snd1 = (hi & 1) ? p01 : p11;
      unsigned rcv0 = __shfl_xor(snd0, 16);
      unsigned rcv1 = __shfl_xor(snd1, 16);
      U8 pu;
      pu.u[0] = ofirst ? own0 : rcv0;
      pu.u[1] = ofirst ? own1 : rcv1;
      pu.u[2] = ofirst ? rcv0 : own0;
      pu.u[3] = ofirst ? rcv1 : own1;
      const int slotbase = c * 4 + (hi & 1) * 2 + (hi >> 1);  // V octet slot
      __builtin_amdgcn_s_setprio(1);
#pragma unroll
      for (int fd = 0; fd < 4; ++fd) {
        int vrow = fd * 16 + l15;
        bf16x8 vf = *(const bf16x8*)(Vb + vrow * 64 + ((slotbase ^ (vrow & 7)) * 8));
        Of[fd] = MFMA16(vf, pu.v, Of[fd]);  // O^T = V^T * P^T
      }
      __builtin_amdgcn_s_setprio(0);
    }
  };

  stage(0, 0);
  int cur = 0;
  for (int kt = 0; kt < 14; ++kt) {  // full tiles, no masking
    stage(kt + 1, cur ^ 1);
    asm volatile("s_waitcnt vmcnt(4)" ::: "memory");
    asm volatile("s_barrier" ::: "memory");
    tilecomp(K_lds[cur], V_lds[cur], false);
    asm volatile("s_barrier" ::: "memory");
    cur ^= 1;
  }
  asm volatile("s_waitcnt vmcnt(0)" ::: "memory");
  asm volatile("s_barrier" ::: "memory");
  tilecomp(K_lds[cur], V_lds[cur], true);

  // deferred softmax-denominator reduction (sum is linear; exact)
  float l_run = l_part;
  l_run += __shfl_xor(l_run, 16);
  l_run += __shfl_xor(l_run, 32);

  const int bq = bh / HH, hq = bh - bq * HH;
  const int lq = w * 16 + l15;
  if (lq < qn) {
    float inv = 1.0f / l_run;
    size_t rowo = ((size_t)(bq * NN + q0 + lq)) * CC + hq * 64;
#pragma unroll
    for (int fd = 0; fd < 4; ++fd) {
      uint2 st;
      st.x = pack2(Of[fd][0] * inv, Of[fd][1] * inv);
      st.y = pack2(Of[fd][2] * inv, Of[fd][3] * inv);
      *(uint2*)(AO + rowo + fd * 16 + hi * 4) = st;
    }
  }
}

// -------- output projection GEMM + bias (fp32 out), 64x128 tiles, XCD-chunked --------
__global__ __launch_bounds__(256, 3) void gemm_out64(
    const __bf16* __restrict__ AO, const __bf16* __restrict__ WPt,
    const float* __restrict__ bias, float* __restrict__ Out) {
  __shared__ alignas(16) __bf16 L[2 * 12288];  // per buf: A 64x64 (4096) + B 128x64 (8192)

  const int tid = threadIdx.x;
  const int w = tid >> 6, l = tid & 63;
  const int l15 = l & 15, hi = l >> 4;
  const int wr = (w >> 1) * 32, wc = (w & 1) * 64;

  // m204 bijective XCD chunking: nwg=1362, q=170, r=2
  const int bid = blockIdx.x;
  const int xcd = bid & 7;
  const int base = (xcd < 2) ? xcd * 171 : 2 * 171 + (xcd - 2) * 170;
  const int wgid = base + (bid >> 3);
  const int mt = wgid / 6, nt = wgid % 6;
  const int m0 = mt * 64, nc = nt * 128;
  const __bf16* bt = WPt + (size_t)nc * CC;

  const int srow = tid >> 3, sslot = tid & 7;  // 32 row-groups x 8 slots
  const __bf16* ga[2]; const __bf16* gb[4]; int lofsA[2], lofsB[4];
#pragma unroll
  for (int j = 0; j < 2; ++j) {
    int row = j * 32 + srow;
    int co = (sslot ^ (row & 7)) * 8;
    int arow = m0 + row; arow = arow < MTOK ? arow : MTOK - 1;
    ga[j] = AO + (size_t)arow * CC + co;
    lofsA[j] = row * 64 + sslot * 8;
  }
#pragma unroll
  for (int j = 0; j < 4; ++j) {
    int row = j * 32 + srow;
    int co = (sslot ^ (row & 7)) * 8;
    gb[j] = bt + (size_t)row * CC + co;
    lofsB[j] = 4096 + row * 64 + sslot * 8;
  }

  f32x4 acc[2][4] = {};

#define STAGE_(buf)                                                            \
  {                                                                            \
    _Pragma("unroll") for (int j = 0; j < 2; ++j) {                            \
      glds16(ga[j], L + (buf) * 12288 + lofsA[j]); ga[j] += 64;                \
    }                                                                          \
    _Pragma("unroll") for (int j = 0; j < 4; ++j) {                            \
      glds16(gb[j], L + (buf) * 12288 + lofsB[j]); gb[j] += 64;                \
    }                                                                          \
  }

#define COMP_(buf)                                                             \
  {                                                                            \
    _Pragma("unroll") for (int kks = 0; kks < 2; ++kks) {                      \
      bf16x8 af[2], bfr[4];                                                    \
      _Pragma("unroll") for (int mf = 0; mf < 2; ++mf) {                       \
        int rowa = wr + mf * 16 + l15;                                         \
        af[mf] = *(const bf16x8*)(L + (buf) * 12288 + rowa * 64 +              \
                                  (((kks * 4 + hi) ^ (rowa & 7)) * 8));        \
      }                                                                        \
      _Pragma("unroll") for (int nf = 0; nf < 4; ++nf) {                       \
        int rowb = wc + nf * 16 + l15;                                         \
        bfr[nf] = *(const bf16x8*)(L + (buf) * 12288 + 4096 + rowb * 64 +      \
                                   (((kks * 4 + hi) ^ (rowb & 7)) * 8));       \
      }                                                                        \
      __builtin_amdgcn_s_setprio(1);                                           \
      _Pragma("unroll") for (int mf = 0; mf < 2; ++mf)                         \
          _Pragma("unroll") for (int nf = 0; nf < 4; ++nf)                     \
              acc[mf][nf] = MFMA16(af[mf], bfr[nf], acc[mf][nf]);              \
      __builtin_amdgcn_s_setprio(0);                                           \
    }                                                                          \
  }

  STAGE_(0);  // tile 0 -> 6 loads in flight

#pragma unroll
  for (int t = 0; t < 12; ++t) {
    if (t < 11) {
      STAGE_((t + 1) & 1);  // 12 in flight
      asm volatile("s_waitcnt vmcnt(6)" ::: "memory");  // retire tile t only
    } else {
      asm volatile("s_waitcnt vmcnt(0)" ::: "memory");
    }
    asm volatile("s_barrier" ::: "memory");
    COMP_(t & 1);
    asm volatile("s_barrier" ::: "memory");
  }
#undef STAGE_
#undef COMP_

#pragma unroll
  for (int mf = 0; mf < 2; ++mf) {
#pragma unroll
    for (int r = 0; r < 4; ++r) {
      int token = m0 + wr + mf * 16 + hi * 4 + r;
      if (token >= MTOK) continue;
#pragma unroll
      for (int nf = 0; nf < 4; ++nf) {
        int col = nc + wc + nf * 16 + l15;
        Out[(size_t)token * CC + col] = acc[mf][nf][r] + bias[col];
      }
    }
  }
}

extern "C" void kernel_launch(void* const* d_in, const int* in_sizes, int n_in,
                              void* d_out, int out_size, void* d_ws, size_t ws_size,
                              hipStream_t stream) {
  (void)in_sizes; (void)n_in; (void)out_size;
  const float* x   = (const float*)d_in[0];
  const float* Wq  = (const float*)d_in[1];
  const float* Wk  = (const float*)d_in[2];
  const float* Wv  = (const float*)d_in[3];
  const float* Wvc = (const float*)d_in[4];
  const float* Wp  = (const float*)d_in[5];
  const float* bp  = (const float*)d_in[6];
  float* out = (float*)d_out;

  const size_t SZ_TOK = (size_t)TOKC * 2;
  const size_t SZ_W   = (size_t)CC * CC * 2;
  const size_t NEED   = SZ_TOK * 6 + SZ_W * 5;
  if (ws_size < NEED) return;

  char* ws = (char*)d_ws;
  __bf16* xb  = (__bf16*)ws;
  __bf16* wt  = (__bf16*)(ws + SZ_TOK);
  __bf16* qb  = (__bf16*)(ws + SZ_TOK + 5 * SZ_W);
  __bf16* kb  = qb + TOKC;
  __bf16* vab = kb + TOKC;
  __bf16* vvb = vab + TOKC;
  __bf16* aob = vvb + TOKC;

  cvt_all_kernel<<<CVTX_BLOCKS + CVTW_BLOCKS, 256, 0, stream>>>(
      x, xb, Wq, Wk, Wv, Wvc, Wp, wt);
  gemm_qkv256<<<dim3(12, 57), 512, 0, stream>>>(xb, wt, qb, kb, vab, vvb);
  attn_kernel<<<3072, 256, 0, stream>>>(qb, kb, vab, vvb, aob);
  gemm_out64<<<1362, 256, 0, stream>>>(aob, wt + 4 * (size_t)(CC * CC), bp, out);
}

// Round 17
// 228.329 us; speedup vs baseline: 1.1262x; 1.1262x over previous
//
#include <hip/hip_runtime.h>

typedef __attribute__((ext_vector_type(8))) __bf16 bf16x8;
typedef __attribute__((ext_vector_type(4))) float f32x4;

constexpr int BB = 16, NN = 906, CC = 768, HH = 12, MM1 = 513;
constexpr int MTOK = BB * NN;      // 14496 tokens
constexpr int TOKC = MTOK * CC;    // 11132928 elements

#define MFMA16(a, b, c) __builtin_amdgcn_mfma_f32_16x16x32_bf16((a), (b), (c), 0, 0, 0)

__device__ __forceinline__ void glds16(const void* g, void* l) {
  __builtin_amdgcn_global_load_lds(
      (const __attribute__((address_space(1))) void*)g,
      (__attribute__((address_space(3))) void*)l, 16, 0, 0);
}

__device__ __forceinline__ unsigned pack2(float a, float b) {
  unsigned short ua = __builtin_bit_cast(unsigned short, (__bf16)a);
  unsigned short ub = __builtin_bit_cast(unsigned short, (__bf16)b);
  return (unsigned)ua | ((unsigned)ub << 16);
}

union U8 { unsigned u[4]; bf16x8 v; };

// ------- merged convert kernel: blocks [0,5436) cvt_x ; [5436,8316) cvt_w -------
constexpr int CVTX_BLOCKS = TOKC / 2048;          // 5436
constexpr int CVTW_BLOCKS = 24 * 24 * 5;          // 2880
__global__ __launch_bounds__(256) void cvt_all_kernel(
    const float* __restrict__ x, __bf16* __restrict__ xb,
    const float* __restrict__ W0, const float* __restrict__ W1,
    const float* __restrict__ W2, const float* __restrict__ W3,
    const float* __restrict__ W4, __bf16* __restrict__ wout) {
  __shared__ float t[32][33];
  const int bid = blockIdx.x;
  if (bid < CVTX_BLOCKS) {
    long i = (long)bid * 256 + threadIdx.x;
    const float4* p = (const float4*)x + i * 2;
    float4 a = p[0], b = p[1];
    bf16x8 o;
    o[0] = (__bf16)a.x; o[1] = (__bf16)a.y; o[2] = (__bf16)a.z; o[3] = (__bf16)a.w;
    o[4] = (__bf16)b.x; o[5] = (__bf16)b.y; o[6] = (__bf16)b.z; o[7] = (__bf16)b.w;
    *(bf16x8*)(xb + i * 8) = o;
  } else {
    int wb = bid - CVTX_BLOCKS;
    int z = wb / 576, rem = wb - z * 576;
    int by = rem / 24, bx = rem - by * 24;
    const float* src = z == 0 ? W0 : z == 1 ? W1 : z == 2 ? W2 : z == 3 ? W3 : W4;
    __bf16* dst = wout + (size_t)z * CC * CC;
    int x0 = bx * 32, y0 = by * 32;
    int tx = threadIdx.x & 31, ty = threadIdx.x >> 5;  // ty 0..7
#pragma unroll
    for (int i = 0; i < 4; ++i)
      t[ty + i * 8][tx] = src[(size_t)(y0 + ty + i * 8) * CC + x0 + tx];
    __syncthreads();
#pragma unroll
    for (int i = 0; i < 4; ++i)
      dst[(size_t)(x0 + ty + i * 8) * CC + y0 + tx] = (__bf16)t[tx][ty + i * 8];
  }
}

// -- Schedule-B 128x128x768 GEMM mainloop: 2 LDS buffers (64 KB, 2 blocks/CU), --
// -- counted vmcnt(8), full-iteration prefetch distance, 2 barriers/iter.      --
// NOTE (r16): 2 blocks/CU is the load-bearing property — at 1 block/CU the
// stage+vmcnt+barrier serial path is fully exposed (3x measured regressions).
__device__ __forceinline__ void gemm_core_db2(const __bf16* __restrict__ A,
                                              const __bf16* __restrict__ Bt,
                                              __bf16* __restrict__ L,
                                              int m0, int M, f32x4 acc[4][4]) {
  const int tid = threadIdx.x;
  const int w = tid >> 6, l = tid & 63;
  const int l15 = l & 15, hi = l >> 4;
  const int wr = (w >> 1) * 64, wc = (w & 1) * 64;
  const int srow = l >> 3, sslot = l & 7;

  const __bf16* ga[4]; const __bf16* gb[4]; int lofs[4];
#pragma unroll
  for (int rr = 0; rr < 4; ++rr) {
    int row = rr * 32 + w * 8 + srow;
    int co = (sslot ^ (row & 7)) * 8;
    int arow = m0 + row; arow = arow < M ? arow : M - 1;
    ga[rr] = A + (size_t)arow * CC + co;
    gb[rr] = Bt + (size_t)row * CC + co;
    lofs[rr] = row * 64 + sslot * 8;
  }

#define STAGE_(buf)                                                            \
  {                                                                            \
    _Pragma("unroll") for (int rr = 0; rr < 4; ++rr) {                         \
      glds16(ga[rr], L + (buf) * 16384 + lofs[rr]);                            \
      glds16(gb[rr], L + (buf) * 16384 + 8192 + lofs[rr]);                     \
      ga[rr] += 64; gb[rr] += 64;                                              \
    }                                                                          \
  }

#define COMP_(buf)                                                             \
  {                                                                            \
    _Pragma("unroll") for (int kks = 0; kks < 2; ++kks) {                      \
      bf16x8 af[4], bfr[4];                                                    \
      _Pragma("unroll") for (int mf = 0; mf < 4; ++mf) {                       \
        int rowa = wr + mf * 16 + l15;                                         \
        af[mf] = *(const bf16x8*)(L + (buf) * 16384 + rowa * 64 +              \
                                  (((kks * 4 + hi) ^ (rowa & 7)) * 8));        \
      }                                                                        \
      _Pragma("unroll") for (int nf = 0; nf < 4; ++nf) {                       \
        int rowb = wc + nf * 16 + l15;                                         \
        bfr[nf] = *(const bf16x8*)(L + (buf) * 16384 + 8192 + rowb * 64 +      \
                                   (((kks * 4 + hi) ^ (rowb & 7)) * 8));       \
      }                                                                        \
      __builtin_amdgcn_s_setprio(1);                                           \
      _Pragma("unroll") for (int mf = 0; mf < 4; ++mf)                         \
          _Pragma("unroll") for (int nf = 0; nf < 4; ++nf)                     \
              acc[mf][nf] = MFMA16(af[mf], bfr[nf], acc[mf][nf]);              \
      __builtin_amdgcn_s_setprio(0);                                           \
    }                                                                          \
  }

  STAGE_(0);  // tile 0 -> 8 loads in flight

#pragma unroll
  for (int t = 0; t < 12; ++t) {
    if (t < 11) {
      STAGE_((t + 1) & 1);  // now 16 in flight
      asm volatile("s_waitcnt vmcnt(8)" ::: "memory");  // retire tile t only
    } else {
      asm volatile("s_waitcnt vmcnt(0)" ::: "memory");
    }
    asm volatile("s_barrier" ::: "memory");
    COMP_(t & 1);
    asm volatile("s_barrier" ::: "memory");  // close reads before next overwrite
  }
#undef STAGE_
#undef COMP_
}

// ---------------- QKV(+Vc) projection GEMM (proven 128² config) ----------------
// q pre-scaled by d^-1/2 * log2(e) so attention can use native exp2.
__global__ __launch_bounds__(256, 2) void gemm_qkv(
    const __bf16* __restrict__ Xb, const __bf16* __restrict__ WT,
    __bf16* __restrict__ Qb, __bf16* __restrict__ Kb,
    __bf16* __restrict__ VAb, __bf16* __restrict__ VVb) {
  __shared__ alignas(16) __bf16 L[2 * 16384];
  int nt = blockIdx.x, mt = blockIdx.y;
  int m0 = mt * 128;
  int wi = nt / 6, nc = (nt % 6) * 128;
  const __bf16* bt = WT + (size_t)wi * (CC * CC) + (size_t)nc * CC;
  f32x4 acc[4][4] = {};
  gemm_core_db2(Xb, bt, L, m0, MTOK, acc);

  const int tid = threadIdx.x;
  const int w = tid >> 6, l = tid & 63, l15 = l & 15, hi = l >> 4;
  const int wr = (w >> 1) * 64, wc = (w & 1) * 64;
  const float qs = (wi == 0) ? 0.1803368801f : 1.0f;  // 0.125 * log2(e)
#pragma unroll
  for (int mf = 0; mf < 4; ++mf) {
#pragma unroll
    for (int r = 0; r < 4; ++r) {
      int token = m0 + wr + mf * 16 + hi * 4 + r;
      if (token >= MTOK) continue;
      int b = token / NN, n = token - b * NN;
#pragma unroll
      for (int nf = 0; nf < 4; ++nf) {
        int col = nc + wc + nf * 16 + l15;
        int h = col >> 6, dd = col & 63;
        __bf16 bv = (__bf16)(acc[mf][nf][r] * qs);
        size_t bhd = (size_t)(b * HH + h);
        if (wi == 0)      Qb[(bhd * NN + n) * 64 + dd] = bv;
        else if (wi == 1) Kb[(bhd * NN + n) * 64 + dd] = bv;
        else if (wi == 2) ((n < MM1) ? VAb : VVb)[(bhd * 64 + dd) * NN + n] = bv;
        else              ((n < MM1) ? VVb : VAb)[(bhd * 64 + dd) * NN + n] = bv;
      }
    }
  }
}

// ---------------- flash attention (round-8 structure + XCD-chunked swizzle) ----------------
__global__ __launch_bounds__(256, 2) void attn_kernel(
    const __bf16* __restrict__ Q, const __bf16* __restrict__ K,
    const __bf16* __restrict__ VA, const __bf16* __restrict__ VV,
    __bf16* __restrict__ AO) {
  __shared__ alignas(16) __bf16 K_lds[2][64 * 64];
  __shared__ alignas(16) __bf16 V_lds[2][64 * 64];  // [dd][key]

  const int tid = threadIdx.x;
  const int w = tid >> 6, l = tid & 63;
  const int l15 = l & 15, hi = l >> 4;

  // XCD-chunked decode: bid -> (bh, tile)
  const int bid = blockIdx.x;
  const int xcd = bid & 7, slot = bid >> 3;     // slot 0..383
  const int bh = xcd * 24 + (slot >> 4);        // contiguous 24-head range per XCD
  const int tile = slot & 15;

  int q0, qn; bool mod1;
  if (tile < 9) { q0 = tile * 64; qn = min(64, MM1 - q0); mod1 = true; }
  else { q0 = MM1 + (tile - 9) * 64; qn = min(64, NN - q0); mod1 = false; }

  const __bf16* qp = Q + (size_t)bh * NN * 64;
  const __bf16* kp = K + (size_t)bh * NN * 64;
  const __bf16* vp = (mod1 ? VA : VV) + (size_t)bh * 64 * NN;

  int qrow = q0 + w * 16 + l15; qrow = qrow < NN ? qrow : NN - 1;
  bf16x8 qf0 = *(const bf16x8*)(qp + (size_t)qrow * 64 + hi * 8);
  bf16x8 qf1 = *(const bf16x8*)(qp + (size_t)qrow * 64 + 32 + hi * 8);

  f32x4 Of[4] = {};
  float l_part = 0.f;  // lane-local; reduced once at epilogue

  const int srow = l >> 3, sslot = l & 7;
  auto stage = [&](int kt, int buf) {
    int k0s = kt * 64;
#pragma unroll
    for (int rr = 0; rr < 2; ++rr) {
      int row = rr * 32 + w * 8 + srow;
      int krow = k0s + row; krow = krow < NN ? krow : NN - 1;  // dup key, masked
      glds16(kp + (size_t)krow * 64 + ((sslot ^ (row & 7)) * 8),
             &K_lds[buf][row * 64 + sslot * 8]);
      int vcol = k0s + ((sslot ^ (row & 7)) * 8);  // tail overrun: P=0 there
      glds16(vp + (size_t)row * NN + vcol, &V_lds[buf][row * 64 + sslot * 8]);
    }
  };

  const bool ofirst = ((hi & 1) == 0);
  auto tilecomp = [&](const __bf16* Kb, const __bf16* Vb, bool maskTail) {
    f32x4 sa[4] = {};
    __builtin_amdgcn_s_setprio(1);
#pragma unroll
    for (int kks = 0; kks < 2; ++kks) {
#pragma unroll
      for (int f = 0; f < 4; ++f) {
        int rk = f * 16 + l15;
        bf16x8 kf = *(const bf16x8*)(Kb + rk * 64 + (((kks * 4 + hi) ^ (rk & 7)) * 8));
        sa[f] = MFMA16(kf, (kks ? qf1 : qf0), sa[f]);
      }
    }
    __builtin_amdgcn_s_setprio(0);

    if (maskTail) {
#pragma unroll
      for (int f = 0; f < 4; ++f) {
        int keyb = 896 + f * 16 + hi * 4;
#pragma unroll
        for (int r = 0; r < 4; ++r)
          if (keyb + r >= NN) sa[f][r] = -1e30f;
      }
    }

#pragma unroll
    for (int f = 0; f < 4; ++f)
#pragma unroll
      for (int r = 0; r < 4; ++r) {
        sa[f][r] = __builtin_amdgcn_exp2f(sa[f][r]);
        l_part += sa[f][r];
      }

#pragma unroll
    for (int c = 0; c < 2; ++c) {
      unsigned p00 = pack2(sa[c * 2][0], sa[c * 2][1]);
      unsigned p01 = pack2(sa[c * 2][2], sa[c * 2][3]);
      unsigned p10 = pack2(sa[c * 2 + 1][0], sa[c * 2 + 1][1]);
      unsigned p11 = pack2(sa[c * 2 + 1][2], sa[c * 2 + 1][3]);
      unsigned own0 = (hi & 1) ? p10 : p00;
      unsigned own1 = (hi & 1) ? p11 : p01;
      unsigned snd0 = (hi & 1) ? p00 : p10;
      unsigned snd1 = (hi & 1) ? p01 : p11;
      unsigned rcv0 = __shfl_xor(snd0, 16);
      unsigned rcv1 = __shfl_xor(snd1, 16);
      U8 pu;
      pu.u[0] = ofirst ? own0 : rcv0;
      pu.u[1] = ofirst ? own1 : rcv1;
      pu.u[2] = ofirst ? rcv0 : own0;
      pu.u[3] = ofirst ? rcv1 : own1;
      const int slotbase = c * 4 + (hi & 1) * 2 + (hi >> 1);  // V octet slot
      __builtin_amdgcn_s_setprio(1);
#pragma unroll
      for (int fd = 0; fd < 4; ++fd) {
        int vrow = fd * 16 + l15;
        bf16x8 vf = *(const bf16x8*)(Vb + vrow * 64 + ((slotbase ^ (vrow & 7)) * 8));
        Of[fd] = MFMA16(vf, pu.v, Of[fd]);  // O^T = V^T * P^T
      }
      __builtin_amdgcn_s_setprio(0);
    }
  };

  stage(0, 0);
  int cur = 0;
  for (int kt = 0; kt < 14; ++kt) {  // full tiles, no masking
    stage(kt + 1, cur ^ 1);
    asm volatile("s_waitcnt vmcnt(4)" ::: "memory");
    asm volatile("s_barrier" ::: "memory");
    tilecomp(K_lds[cur], V_lds[cur], false);
    asm volatile("s_barrier" ::: "memory");
    cur ^= 1;
  }
  asm volatile("s_waitcnt vmcnt(0)" ::: "memory");
  asm volatile("s_barrier" ::: "memory");
  tilecomp(K_lds[cur], V_lds[cur], true);

  // deferred softmax-denominator reduction (sum is linear; exact)
  float l_run = l_part;
  l_run += __shfl_xor(l_run, 16);
  l_run += __shfl_xor(l_run, 32);

  const int bq = bh / HH, hq = bh - bq * HH;
  const int lq = w * 16 + l15;
  if (lq < qn) {
    float inv = 1.0f / l_run;
    size_t rowo = ((size_t)(bq * NN + q0 + lq)) * CC + hq * 64;
#pragma unroll
    for (int fd = 0; fd < 4; ++fd) {
      uint2 st;
      st.x = pack2(Of[fd][0] * inv, Of[fd][1] * inv);
      st.y = pack2(Of[fd][2] * inv, Of[fd][3] * inv);
      *(uint2*)(AO + rowo + fd * 16 + hi * 4) = st;
    }
  }
}

// -------- output projection GEMM + bias (fp32 out), 64x128 tiles, XCD-chunked --------
__global__ __launch_bounds__(256, 3) void gemm_out64(
    const __bf16* __restrict__ AO, const __bf16* __restrict__ WPt,
    const float* __restrict__ bias, float* __restrict__ Out) {
  __shared__ alignas(16) __bf16 L[2 * 12288];  // per buf: A 64x64 (4096) + B 128x64 (8192)

  const int tid = threadIdx.x;
  const int w = tid >> 6, l = tid & 63;
  const int l15 = l & 15, hi = l >> 4;
  const int wr = (w >> 1) * 32, wc = (w & 1) * 64;

  // m204 bijective XCD chunking: nwg=1362, q=170, r=2
  const int bid = blockIdx.x;
  const int xcd = bid & 7;
  const int base = (xcd < 2) ? xcd * 171 : 2 * 171 + (xcd - 2) * 170;
  const int wgid = base + (bid >> 3);
  const int mt = wgid / 6, nt = wgid % 6;
  const int m0 = mt * 64, nc = nt * 128;
  const __bf16* bt = WPt + (size_t)nc * CC;

  const int srow = tid >> 3, sslot = tid & 7;  // 32 row-groups x 8 slots
  const __bf16* ga[2]; const __bf16* gb[4]; int lofsA[2], lofsB[4];
#pragma unroll
  for (int j = 0; j < 2; ++j) {
    int row = j * 32 + srow;
    int co = (sslot ^ (row & 7)) * 8;
    int arow = m0 + row; arow = arow < MTOK ? arow : MTOK - 1;
    ga[j] = AO + (size_t)arow * CC + co;
    lofsA[j] = row * 64 + sslot * 8;
  }
#pragma unroll
  for (int j = 0; j < 4; ++j) {
    int row = j * 32 + srow;
    int co = (sslot ^ (row & 7)) * 8;
    gb[j] = bt + (size_t)row * CC + co;
    lofsB[j] = 4096 + row * 64 + sslot * 8;
  }

  f32x4 acc[2][4] = {};

#define STAGE_(buf)                                                            \
  {                                                                            \
    _Pragma("unroll") for (int j = 0; j < 2; ++j) {                            \
      glds16(ga[j], L + (buf) * 12288 + lofsA[j]); ga[j] += 64;                \
    }                                                                          \
    _Pragma("unroll") for (int j = 0; j < 4; ++j) {                            \
      glds16(gb[j], L + (buf) * 12288 + lofsB[j]); gb[j] += 64;                \
    }                                                                          \
  }

#define COMP_(buf)                                                             \
  {                                                                            \
    _Pragma("unroll") for (int kks = 0; kks < 2; ++kks) {                      \
      bf16x8 af[2], bfr[4];                                                    \
      _Pragma("unroll") for (int mf = 0; mf < 2; ++mf) {                       \
        int rowa = wr + mf * 16 + l15;                                         \
        af[mf] = *(const bf16x8*)(L + (buf) * 12288 + rowa * 64 +              \
                                  (((kks * 4 + hi) ^ (rowa & 7)) * 8));        \
      }                                                                        \
      _Pragma("unroll") for (int nf = 0; nf < 4; ++nf) {                       \
        int rowb = wc + nf * 16 + l15;                                         \
        bfr[nf] = *(const bf16x8*)(L + (buf) * 12288 + 4096 + rowb * 64 +      \
                                   (((kks * 4 + hi) ^ (rowb & 7)) * 8));       \
      }                                                                        \
      __builtin_amdgcn_s_setprio(1);                                           \
      _Pragma("unroll") for (int mf = 0; mf < 2; ++mf)                         \
          _Pragma("unroll") for (int nf = 0; nf < 4; ++nf)                     \
              acc[mf][nf] = MFMA16(af[mf], bfr[nf], acc[mf][nf]);              \
      __builtin_amdgcn_s_setprio(0);                                           \
    }                                                                          \
  }

  STAGE_(0);  // tile 0 -> 6 loads in flight

#pragma unroll
  for (int t = 0; t < 12; ++t) {
    if (t < 11) {
      STAGE_((t + 1) & 1);  // 12 in flight
      asm volatile("s_waitcnt vmcnt(6)" ::: "memory");  // retire tile t only
    } else {
      asm volatile("s_waitcnt vmcnt(0)" ::: "memory");
    }
    asm volatile("s_barrier" ::: "memory");
    COMP_(t & 1);
    asm volatile("s_barrier" ::: "memory");
  }
#undef STAGE_
#undef COMP_

#pragma unroll
  for (int mf = 0; mf < 2; ++mf) {
#pragma unroll
    for (int r = 0; r < 4; ++r) {
      int token = m0 + wr + mf * 16 + hi * 4 + r;
      if (token >= MTOK) continue;
#pragma unroll
      for (int nf = 0; nf < 4; ++nf) {
        int col = nc + wc + nf * 16 + l15;
        Out[(size_t)token * CC + col] = acc[mf][nf][r] + bias[col];
      }
    }
  }
}

extern "C" void kernel_launch(void* const* d_in, const int* in_sizes, int n_in,
                              void* d_out, int out_size, void* d_ws, size_t ws_size,
                              hipStream_t stream) {
  (void)in_sizes; (void)n_in; (void)out_size;
  const float* x   = (const float*)d_in[0];
  const float* Wq  = (const float*)d_in[1];
  const float* Wk  = (const float*)d_in[2];
  const float* Wv  = (const float*)d_in[3];
  const float* Wvc = (const float*)d_in[4];
  const float* Wp  = (const float*)d_in[5];
  const float* bp  = (const float*)d_in[6];
  float* out = (float*)d_out;

  const size_t SZ_TOK = (size_t)TOKC * 2;
  const size_t SZ_W   = (size_t)CC * CC * 2;
  const size_t NEED   = SZ_TOK * 6 + SZ_W * 5;
  if (ws_size < NEED) return;

  char* ws = (char*)d_ws;
  __bf16* xb  = (__bf16*)ws;
  __bf16* wt  = (__bf16*)(ws + SZ_TOK);
  __bf16* qb  = (__bf16*)(ws + SZ_TOK + 5 * SZ_W);
  __bf16* kb  = qb + TOKC;
  __bf16* vab = kb + TOKC;
  __bf16* vvb = vab + TOKC;
  __bf16* aob = vvb + TOKC;

  cvt_all_kernel<<<CVTX_BLOCKS + CVTW_BLOCKS, 256, 0, stream>>>(
      x, xb, Wq, Wk, Wv, Wvc, Wp, wt);
  gemm_qkv<<<dim3(24, 114), 256, 0, stream>>>(xb, wt, qb, kb, vab, vvb);
  attn_kernel<<<3072, 256, 0, stream>>>(qb, kb, vab, vvb, aob);
  gemm_out64<<<1362, 256, 0, stream>>>(aob, wt + 4 * (size_t)(CC * CC), bp, out);
}